// Round 4
// baseline (130.519 us; speedup 1.0000x reference)
//
#include <hip/hip_runtime.h>
#include <hip/hip_bf16.h>
#include <math.h>

#define N 8192
#define D 128
#define MARGIN 0.3f

#define NSTRIP 64            // 128-row strips
#define CPS 8                // j-chunks per strip
#define TPC 16               // 64-col j-tiles per chunk (8*16 = 128, uniform)
#define GRID_MAIN (NSTRIP * CPS)   // 512 = exactly 2 blocks/CU

typedef float f32x4 __attribute__((ext_vector_type(4)));
typedef short bf16x8 __attribute__((ext_vector_type(8)));
typedef unsigned short u16x8 __attribute__((ext_vector_type(8)));

__device__ inline unsigned short f2bf(float f) {
    unsigned u = __float_as_uint(f);
    unsigned r = (u + 0x7FFFu + ((u >> 16) & 1u)) >> 16;
    return (unsigned short)r;
}

// ---------- convert fp32 -> bf16 + row norms + init mining arrays ----------
__global__ __launch_bounds__(256) void convert_kernel(const float* __restrict__ X,
                                                      unsigned short* __restrict__ Xb,
                                                      float* __restrict__ sq,
                                                      unsigned* __restrict__ ap2,
                                                      unsigned* __restrict__ an2) {
    int tid = threadIdx.x;
    int row = blockIdx.x * 16 + (tid >> 4);
    int l = tid & 15;
    const float4* p = reinterpret_cast<const float4*>(X + (size_t)row * D + l * 8);
    float4 u = p[0];
    float4 v = p[1];
    float s = u.x*u.x + u.y*u.y + u.z*u.z + u.w*u.w
            + v.x*v.x + v.y*v.y + v.z*v.z + v.w*v.w;
    u16x8 o;
    o[0] = f2bf(u.x); o[1] = f2bf(u.y); o[2] = f2bf(u.z); o[3] = f2bf(u.w);
    o[4] = f2bf(v.x); o[5] = f2bf(v.y); o[6] = f2bf(v.z); o[7] = f2bf(v.w);
    *reinterpret_cast<u16x8*>(Xb + (size_t)row * D + l * 8) = o;
    #pragma unroll
    for (int off = 8; off >= 1; off >>= 1) s += __shfl_xor(s, off);
    if (l == 0) {
        sq[row] = s;
        ap2[row] = 0u;            // 0.0f  (< any clipped d2)
        an2[row] = 0x7F7F7F7Fu;   // huge  (> any d2)
    }
}

// ---------- main: full-Gram, i-mining only, NO LDS, NO BARRIERS ----------
// The MFMA bf16 16x16x32 A/B fragment for lane (quad,lx) is 16 CONTIGUOUS
// bytes of Xb (row r, elements ks*32+quad*8 ..+8); per 16-lane quad-group the
// 4 quads cover one whole 64-B line of a row -> perfectly line-coalesced
// direct global loads. Xb (2 MB) is L2-resident per XCD, so LDS staging was
// pure overhead: round-3's LDS pipe carried 64 KB of ds_read per 16 KB tile
// (4 wr-waves re-read each wc-half) + a vmcnt(0) barrier per tile. Loading
// fragments global->VGPR deletes LDS, the double buffer, and every barrier;
// waves run free, L1 catches the 4-way intra-block B reuse (per-tile block
// footprint 16 KB, 2 blocks/CU = 32 KB = L1 size).
// Grid 512 x 512thr = 2 blocks/CU, 16 waves/CU; wave tile 32x32 (wr=w>>1,
// wc=w&1); per-lane addressing is one v_add per tc per tile + imm offsets.
__global__ __launch_bounds__(512, 4) void triplet_main(
        const unsigned short* __restrict__ Xb,
        const int* __restrict__ lbl,
        const float* __restrict__ sq,
        unsigned* __restrict__ ap2,
        unsigned* __restrict__ an2) {
    const int bi = blockIdx.x >> 3;            // /CPS
    const int c  = blockIdx.x & 7;
    const int jt0 = c * TPC;
    const int i0 = bi * 128;

    const int tid = threadIdx.x;
    const int w = tid >> 6;        // wave 0..7
    const int lane = tid & 63;
    const int wr = w >> 1;         // 0..3 : 32-row group
    const int wc = w & 1;          // 0..1 : 32-col group
    const int quad = lane >> 4;
    const int lx = lane & 15;

    // ---- A fragments direct from global: af_r[tr][ks], 32 VGPRs ----
    bf16x8 af_r[2][4];
    #pragma unroll
    for (int tr = 0; tr < 2; ++tr) {
        const char* pa = (const char*)Xb
                       + (size_t)(i0 + wr * 32 + tr * 16 + lx) * (D * 2) + quad * 16;
        #pragma unroll
        for (int ks = 0; ks < 4; ++ks)
            af_r[tr][ks] = *reinterpret_cast<const bf16x8*>(pa + ks * 64);
    }

    // row labels for this wave's 8 accumulator rows
    int lbl_i[8];
    #pragma unroll
    for (int tr = 0; tr < 2; ++tr)
        #pragma unroll
        for (int v = 0; v < 4; ++v)
            lbl_i[tr * 4 + v] = lbl[i0 + wr * 32 + tr * 16 + quad * 4 + v];

    // per-lane column-part offsets (j direction streams via scalar-ish bumps)
    int cb[2];        // element offset of this lane's j column within a tile row
    unsigned cbB[2];  // byte offset of this lane's B-fragment within a tile
    #pragma unroll
    for (int tc = 0; tc < 2; ++tc) {
        cb[tc] = wc * 32 + tc * 16 + lx;
        cbB[tc] = (unsigned)(cb[tc] * (D * 2) + quad * 16);
    }

    float m_ap[8], m_an[8];
    #pragma unroll
    for (int q = 0; q < 8; ++q) { m_ap[q] = -INFINITY; m_an[q] = INFINITY; }
    const f32x4 z4 = {0.f, 0.f, 0.f, 0.f};

    #pragma unroll 1
    for (int tt = 0; tt < TPC; ++tt) {
        const int jj = jt0 + tt;
        const int j64 = jj * 64;                       // scalar
        const unsigned jbyte = (unsigned)j64 * (D * 2);  // scalar

        // per-lane j metadata (one 64-B line per quad-group; L2/L1-hot)
        float sqj[2]; int lblj[2];
        #pragma unroll
        for (int tc = 0; tc < 2; ++tc) {
            int jc = j64 + cb[tc];
            sqj[tc] = sq[jc];
            lblj[tc] = lbl[jc];
        }

        // B fragments direct from global: 8 x 16-B line-coalesced loads
        bf16x8 bf[2][4];
        #pragma unroll
        for (int tc = 0; tc < 2; ++tc) {
            const char* pb = (const char*)Xb + (jbyte + cbB[tc]);
            #pragma unroll
            for (int ks = 0; ks < 4; ++ks)
                bf[tc][ks] = *reinterpret_cast<const bf16x8*>(pb + ks * 64);
        }

        // ---- MFMA: ks=0 peeled with zero-C (no per-tile acc zeroing) ----
        f32x4 acc[2][2];
        #pragma unroll
        for (int tr = 0; tr < 2; ++tr)
            #pragma unroll
            for (int tc = 0; tc < 2; ++tc)
                acc[tr][tc] = __builtin_amdgcn_mfma_f32_16x16x32_bf16(
                    af_r[tr][0], bf[tc][0], z4, 0, 0, 0);
        #pragma unroll
        for (int ks = 1; ks < 4; ++ks)
            #pragma unroll
            for (int tr = 0; tr < 2; ++tr)
                #pragma unroll
                for (int tc = 0; tc < 2; ++tc)
                    acc[tr][tc] = __builtin_amdgcn_mfma_f32_16x16x32_bf16(
                        af_r[tr][ks], bf[tc][ks], acc[tr][tc], 0, 0, 0);

        // ---- epilogue: i-direction masked mining (16 candidates/lane) ----
        #pragma unroll
        for (int tc = 0; tc < 2; ++tc) {
            #pragma unroll
            for (int tr = 0; tr < 2; ++tr) {
                #pragma unroll
                for (int v = 0; v < 4; ++v) {
                    int q = tr * 4 + v;
                    float vi = fmaf(-2.f, acc[tr][tc][v], sqj[tc]);
                    bool same = (lblj[tc] == lbl_i[q]);
                    m_ap[q] = same ? fmaxf(m_ap[q], vi) : m_ap[q];
                    m_an[q] = same ? m_an[q] : fminf(m_an[q], vi);
                }
            }
        }
    }

    // reduce over the 16 j-lanes, then one atomic pair per row (lx==0 lanes)
    #pragma unroll
    for (int off = 8; off >= 1; off >>= 1) {
        #pragma unroll
        for (int q = 0; q < 8; ++q) {
            m_ap[q] = fmaxf(m_ap[q], __shfl_xor(m_ap[q], off));
            m_an[q] = fminf(m_an[q], __shfl_xor(m_an[q], off));
        }
    }
    if (lx == 0) {
        #pragma unroll
        for (int tr = 0; tr < 2; ++tr) {
            #pragma unroll
            for (int v = 0; v < 4; ++v) {
                int q = tr * 4 + v;
                int row = i0 + wr * 32 + tr * 16 + quad * 4 + v;
                float sqi = sq[row];
                float vap = fmaxf(sqi + m_ap[q], 1e-12f);
                float van = fmaxf(sqi + m_an[q], 1e-12f);
                atomicMax(&ap2[row], __float_as_uint(vap));
                atomicMin(&an2[row], __float_as_uint(van));
            }
        }
    }
}

// ---------- finalize: sqrt + hinge + mean ----------
__global__ __launch_bounds__(1024) void finalize_kernel(const unsigned* __restrict__ ap2,
                                                        const unsigned* __restrict__ an2,
                                                        float* __restrict__ out) {
    int tid = threadIdx.x;
    float ls = 0.f, ps = 0.f;
    for (int row = tid; row < N; row += 1024) {
        float ap = sqrtf(__uint_as_float(ap2[row]));
        float an = sqrtf(__uint_as_float(an2[row]));
        ls += fmaxf(0.f, MARGIN - (an - ap));
        ps += (an > ap) ? 1.f : 0.f;
    }
    #pragma unroll
    for (int off = 32; off >= 1; off >>= 1) {
        ls += __shfl_xor(ls, off);
        ps += __shfl_xor(ps, off);
    }
    __shared__ float red[2][16];
    int w = tid >> 6;
    if ((tid & 63) == 0) { red[0][w] = ls; red[1][w] = ps; }
    __syncthreads();
    if (tid == 0) {
        float L = 0.f, P = 0.f;
        #pragma unroll
        for (int i = 0; i < 16; ++i) { L += red[0][i]; P += red[1][i]; }
        out[0] = L / (float)N;
        out[1] = P / (float)N;
    }
}

extern "C" void kernel_launch(void* const* d_in, const int* in_sizes, int n_in,
                              void* d_out, int out_size, void* d_ws, size_t ws_size,
                              hipStream_t stream) {
    const float* X = (const float*)d_in[0];
    const int* lbl = (const int*)d_in[1];
    float* out = (float*)d_out;

    float* sq = (float*)d_ws;                               // N floats
    unsigned* ap2 = (unsigned*)d_ws + N;                    // N uints
    unsigned* an2 = (unsigned*)d_ws + 2 * N;                // N uints
    unsigned short* Xb = (unsigned short*)((char*)d_ws + 3 * N * sizeof(unsigned)); // N*D bf16

    convert_kernel<<<N / 16, 256, 0, stream>>>(X, Xb, sq, ap2, an2);
    triplet_main<<<GRID_MAIN, 512, 0, stream>>>(Xb, lbl, sq, ap2, an2);
    finalize_kernel<<<1, 1024, 0, stream>>>(ap2, an2, out);
}

// Round 5
// 130.221 us; speedup vs baseline: 1.0023x; 1.0023x over previous
//
#include <hip/hip_runtime.h>
#include <hip/hip_bf16.h>
#include <math.h>

#define N 8192
#define D 128
#define MARGIN 0.3f

#define NSTRIP 64            // 128-row strips
#define CPS 8                // j-chunks per strip
#define TPC 16               // 64-col j-tiles per chunk (8*16 = 128, uniform)
#define GRID_MAIN (NSTRIP * CPS)   // 512 = exactly 2 blocks/CU

typedef float f32x4 __attribute__((ext_vector_type(4)));
typedef short bf16x8 __attribute__((ext_vector_type(8)));
typedef unsigned short u16x8 __attribute__((ext_vector_type(8)));

__device__ inline unsigned short f2bf(float f) {
    unsigned u = __float_as_uint(f);
    unsigned r = (u + 0x7FFFu + ((u >> 16) & 1u)) >> 16;
    return (unsigned short)r;
}

// ---------- convert fp32 -> bf16 + row norms + init mining arrays ----------
__global__ __launch_bounds__(256) void convert_kernel(const float* __restrict__ X,
                                                      unsigned short* __restrict__ Xb,
                                                      float* __restrict__ sq,
                                                      unsigned* __restrict__ ap2,
                                                      unsigned* __restrict__ an2) {
    int tid = threadIdx.x;
    int row = blockIdx.x * 16 + (tid >> 4);
    int l = tid & 15;
    const float4* p = reinterpret_cast<const float4*>(X + (size_t)row * D + l * 8);
    float4 u = p[0];
    float4 v = p[1];
    float s = u.x*u.x + u.y*u.y + u.z*u.z + u.w*u.w
            + v.x*v.x + v.y*v.y + v.z*v.z + v.w*v.w;
    u16x8 o;
    o[0] = f2bf(u.x); o[1] = f2bf(u.y); o[2] = f2bf(u.z); o[3] = f2bf(u.w);
    o[4] = f2bf(v.x); o[5] = f2bf(v.y); o[6] = f2bf(v.z); o[7] = f2bf(v.w);
    *reinterpret_cast<u16x8*>(Xb + (size_t)row * D + l * 8) = o;
    #pragma unroll
    for (int off = 8; off >= 1; off >>= 1) s += __shfl_xor(s, off);
    if (l == 0) {
        sq[row] = s;
        ap2[row] = 0u;            // 0.0f  (< any clipped d2)
        an2[row] = 0x7F7F7F7Fu;   // huge  (> any d2)
    }
}

// ---------- main: full-Gram, i-mining only, NO LDS/barriers, reg-pipelined ----------
// Round-4 lesson: direct global->VGPR fragments are correct and cheap (Xb is
// L2-resident, fragments are 16-B contiguous and line-coalesced), but with no
// prefetch the loop serialized on L2 latency (~10% issue util, 72 us). This
// version software-pipelines with prefetch distance 1 in a SINGLE rotating
// register buffer: prologue loads tile 0; per iteration: MFMA consumes bf ->
// issue next-tile loads into bf -> mining epilogue (~130 VALU-cyc) runs while
// the loads fly. 4 waves/SIMD TLP covers the residue. No barriers anywhere.
// Last iteration re-loads the same tile unconditionally (uniform code, result
// discarded) to keep the loop body branch-free.
__global__ __launch_bounds__(512, 4) void triplet_main(
        const unsigned short* __restrict__ Xb,
        const int* __restrict__ lbl,
        const float* __restrict__ sq,
        unsigned* __restrict__ ap2,
        unsigned* __restrict__ an2) {
    const int bi = blockIdx.x >> 3;            // /CPS
    const int c  = blockIdx.x & 7;
    const int jt0 = c * TPC;
    const int i0 = bi * 128;

    const int tid = threadIdx.x;
    const int w = tid >> 6;        // wave 0..7
    const int lane = tid & 63;
    const int wr = w >> 1;         // 0..3 : 32-row group
    const int wc = w & 1;          // 0..1 : 32-col group
    const int quad = lane >> 4;
    const int lx = lane & 15;

    // ---- A fragments direct from global: af_r[tr][ks], 32 VGPRs ----
    bf16x8 af_r[2][4];
    #pragma unroll
    for (int tr = 0; tr < 2; ++tr) {
        const char* pa = (const char*)Xb
                       + (size_t)(i0 + wr * 32 + tr * 16 + lx) * (D * 2) + quad * 16;
        #pragma unroll
        for (int ks = 0; ks < 4; ++ks)
            af_r[tr][ks] = *reinterpret_cast<const bf16x8*>(pa + ks * 64);
    }

    // row labels for this wave's 8 accumulator rows
    int lbl_i[8];
    #pragma unroll
    for (int tr = 0; tr < 2; ++tr)
        #pragma unroll
        for (int v = 0; v < 4; ++v)
            lbl_i[tr * 4 + v] = lbl[i0 + wr * 32 + tr * 16 + quad * 4 + v];

    // per-lane column-part offsets within a tile
    int cb[2];        // element offset of this lane's j column
    unsigned cbB[2];  // byte offset of this lane's B-fragment
    #pragma unroll
    for (int tc = 0; tc < 2; ++tc) {
        cb[tc] = wc * 32 + tc * 16 + lx;
        cbB[tc] = (unsigned)(cb[tc] * (D * 2) + quad * 16);
    }

    float m_ap[8], m_an[8];
    #pragma unroll
    for (int q = 0; q < 8; ++q) { m_ap[q] = -INFINITY; m_an[q] = INFINITY; }
    const f32x4 z4 = {0.f, 0.f, 0.f, 0.f};

    // ---- pipeline prologue: load tile jt0 into the rotating buffers ----
    bf16x8 bf[2][4];
    float sqj[2]; int lblj[2];
    {
        const unsigned jbyte = (unsigned)(jt0 * 64) * (D * 2);
        #pragma unroll
        for (int tc = 0; tc < 2; ++tc) {
            const char* pb = (const char*)Xb + (jbyte + cbB[tc]);
            #pragma unroll
            for (int ks = 0; ks < 4; ++ks)
                bf[tc][ks] = *reinterpret_cast<const bf16x8*>(pb + ks * 64);
            int jc = jt0 * 64 + cb[tc];
            sqj[tc] = sq[jc];
            lblj[tc] = lbl[jc];
        }
    }

    #pragma unroll 1
    for (int tt = 0; tt < TPC; ++tt) {
        // ---- MFMA: consumes bf (vmcnt wait auto-inserted before first use) ----
        f32x4 acc[2][2];
        #pragma unroll
        for (int tr = 0; tr < 2; ++tr)
            #pragma unroll
            for (int tc = 0; tc < 2; ++tc)
                acc[tr][tc] = __builtin_amdgcn_mfma_f32_16x16x32_bf16(
                    af_r[tr][0], bf[tc][0], z4, 0, 0, 0);
        #pragma unroll
        for (int ks = 1; ks < 4; ++ks)
            #pragma unroll
            for (int tr = 0; tr < 2; ++tr)
                #pragma unroll
                for (int tc = 0; tc < 2; ++tc)
                    acc[tr][tc] = __builtin_amdgcn_mfma_f32_16x16x32_bf16(
                        af_r[tr][ks], bf[tc][ks], acc[tr][tc], 0, 0, 0);

        // keep this tile's metadata for mining, then overwrite with prefetch
        float csq[2]; int clb[2];
        #pragma unroll
        for (int tc = 0; tc < 2; ++tc) { csq[tc] = sqj[tc]; clb[tc] = lblj[tc]; }

        // ---- prefetch tile tt+1 into bf/sqj/lblj (clamped on last iter) ----
        {
            const int jn = (tt + 1 < TPC) ? (jt0 + tt + 1) : (jt0 + tt);
            const unsigned jbyte = (unsigned)(jn * 64) * (D * 2);
            #pragma unroll
            for (int tc = 0; tc < 2; ++tc) {
                const char* pb = (const char*)Xb + (jbyte + cbB[tc]);
                #pragma unroll
                for (int ks = 0; ks < 4; ++ks)
                    bf[tc][ks] = *reinterpret_cast<const bf16x8*>(pb + ks * 64);
                int jc = jn * 64 + cb[tc];
                sqj[tc] = sq[jc];
                lblj[tc] = lbl[jc];
            }
        }

        // ---- mining epilogue: hides the prefetch flight ----
        #pragma unroll
        for (int tc = 0; tc < 2; ++tc) {
            #pragma unroll
            for (int tr = 0; tr < 2; ++tr) {
                #pragma unroll
                for (int v = 0; v < 4; ++v) {
                    int q = tr * 4 + v;
                    float vi = fmaf(-2.f, acc[tr][tc][v], csq[tc]);
                    bool same = (clb[tc] == lbl_i[q]);
                    m_ap[q] = same ? fmaxf(m_ap[q], vi) : m_ap[q];
                    m_an[q] = same ? m_an[q] : fminf(m_an[q], vi);
                }
            }
        }
    }

    // reduce over the 16 j-lanes, then one atomic pair per row (lx==0 lanes)
    #pragma unroll
    for (int off = 8; off >= 1; off >>= 1) {
        #pragma unroll
        for (int q = 0; q < 8; ++q) {
            m_ap[q] = fmaxf(m_ap[q], __shfl_xor(m_ap[q], off));
            m_an[q] = fminf(m_an[q], __shfl_xor(m_an[q], off));
        }
    }
    if (lx == 0) {
        #pragma unroll
        for (int tr = 0; tr < 2; ++tr) {
            #pragma unroll
            for (int v = 0; v < 4; ++v) {
                int q = tr * 4 + v;
                int row = i0 + wr * 32 + tr * 16 + quad * 4 + v;
                float sqi = sq[row];
                float vap = fmaxf(sqi + m_ap[q], 1e-12f);
                float van = fmaxf(sqi + m_an[q], 1e-12f);
                atomicMax(&ap2[row], __float_as_uint(vap));
                atomicMin(&an2[row], __float_as_uint(van));
            }
        }
    }
}

// ---------- finalize: sqrt + hinge + mean ----------
__global__ __launch_bounds__(1024) void finalize_kernel(const unsigned* __restrict__ ap2,
                                                        const unsigned* __restrict__ an2,
                                                        float* __restrict__ out) {
    int tid = threadIdx.x;
    float ls = 0.f, ps = 0.f;
    for (int row = tid; row < N; row += 1024) {
        float ap = sqrtf(__uint_as_float(ap2[row]));
        float an = sqrtf(__uint_as_float(an2[row]));
        ls += fmaxf(0.f, MARGIN - (an - ap));
        ps += (an > ap) ? 1.f : 0.f;
    }
    #pragma unroll
    for (int off = 32; off >= 1; off >>= 1) {
        ls += __shfl_xor(ls, off);
        ps += __shfl_xor(ps, off);
    }
    __shared__ float red[2][16];
    int w = tid >> 6;
    if ((tid & 63) == 0) { red[0][w] = ls; red[1][w] = ps; }
    __syncthreads();
    if (tid == 0) {
        float L = 0.f, P = 0.f;
        #pragma unroll
        for (int i = 0; i < 16; ++i) { L += red[0][i]; P += red[1][i]; }
        out[0] = L / (float)N;
        out[1] = P / (float)N;
    }
}

extern "C" void kernel_launch(void* const* d_in, const int* in_sizes, int n_in,
                              void* d_out, int out_size, void* d_ws, size_t ws_size,
                              hipStream_t stream) {
    const float* X = (const float*)d_in[0];
    const int* lbl = (const int*)d_in[1];
    float* out = (float*)d_out;

    float* sq = (float*)d_ws;                               // N floats
    unsigned* ap2 = (unsigned*)d_ws + N;                    // N uints
    unsigned* an2 = (unsigned*)d_ws + 2 * N;                // N uints
    unsigned short* Xb = (unsigned short*)((char*)d_ws + 3 * N * sizeof(unsigned)); // N*D bf16

    convert_kernel<<<N / 16, 256, 0, stream>>>(X, Xb, sq, ap2, an2);
    triplet_main<<<GRID_MAIN, 512, 0, stream>>>(Xb, lbl, sq, ap2, an2);
    finalize_kernel<<<1, 1024, 0, stream>>>(ap2, an2, out);
}

// Round 6
// 113.036 us; speedup vs baseline: 1.1547x; 1.1520x over previous
//
#include <hip/hip_runtime.h>
#include <hip/hip_bf16.h>
#include <math.h>

#define N 8192
#define D 128
#define MARGIN 0.3f

#define NSTRIP 64            // 128-row strips
#define CPS 8                // j-chunks per strip
#define TPC 16               // 64-col j-tiles per chunk (8*16 = 128, uniform)
#define NEP 8                // epochs per chunk (2 tiles per epoch)
#define GRID_MAIN (NSTRIP * CPS)   // 512 = exactly 2 blocks/CU

typedef float f32x4 __attribute__((ext_vector_type(4)));
typedef short bf16x8 __attribute__((ext_vector_type(8)));
typedef unsigned short u16x8 __attribute__((ext_vector_type(8)));

#define AS1 __attribute__((address_space(1)))
#define AS3 __attribute__((address_space(3)))

__device__ inline void gload_lds16(const void* g, void* l) {
    __builtin_amdgcn_global_load_lds((AS1 void*)(void*)(g), (AS3 void*)(l), 16, 0, 0);
}

__device__ inline unsigned short f2bf(float f) {
    unsigned u = __float_as_uint(f);
    unsigned r = (u + 0x7FFFu + ((u >> 16) & 1u)) >> 16;
    return (unsigned short)r;
}

// ---------- convert fp32 -> bf16 + row norms + init mining arrays ----------
__global__ __launch_bounds__(256) void convert_kernel(const float* __restrict__ X,
                                                      unsigned short* __restrict__ Xb,
                                                      float* __restrict__ sq,
                                                      unsigned* __restrict__ ap2,
                                                      unsigned* __restrict__ an2) {
    int tid = threadIdx.x;
    int row = blockIdx.x * 16 + (tid >> 4);
    int l = tid & 15;
    const float4* p = reinterpret_cast<const float4*>(X + (size_t)row * D + l * 8);
    float4 u = p[0];
    float4 v = p[1];
    float s = u.x*u.x + u.y*u.y + u.z*u.z + u.w*u.w
            + v.x*v.x + v.y*v.y + v.z*v.z + v.w*v.w;
    u16x8 o;
    o[0] = f2bf(u.x); o[1] = f2bf(u.y); o[2] = f2bf(u.z); o[3] = f2bf(u.w);
    o[4] = f2bf(v.x); o[5] = f2bf(v.y); o[6] = f2bf(v.z); o[7] = f2bf(v.w);
    *reinterpret_cast<u16x8*>(Xb + (size_t)row * D + l * 8) = o;
    #pragma unroll
    for (int off = 8; off >= 1; off >>= 1) s += __shfl_xor(s, off);
    if (l == 0) {
        sq[row] = s;
        ap2[row] = 0u;            // 0.0f  (< any clipped d2)
        an2[row] = 0x7F7F7F7Fu;   // huge  (> any d2)
    }
}

// ---------- main: full-Gram, i-mining only, LDS epoch-paired prefetch ----------
// Round-4/5 lesson: direct global->VGPR fragments serialize on L2 latency
// (compiler sinks reg-prefetch loads to their use; 73 us). Round-3's LDS
// version (39 us) stalled on __syncthreads' vmcnt(0) drain arriving ~200cy
// after prefetch issue. This version: 4 x 16 KB LDS buffers; each EPOCH
// computes 2 tiles (~800 cy of ds_read+MFMA+mining) and prefetches the next
// PAIR at epoch top -> the single end-of-epoch __syncthreads drains loads
// issued a full epoch earlier (latency hidden), and barriers halve (16->8).
// Metadata (sq/lbl) prefetched one epoch ahead into slot-rotated registers so
// its compiler wait is a counted, non-draining vmcnt. A-strip staged through
// Bs[0..1] once, held in regs (af_r). 64 KB LDS -> 2 blocks/CU, 16 waves/CU.
// LDS layout per 64-row buffer: chunk slot s of row r holds global chunk
// s^(r&7); read addr = vb ^ (ks<<6) (verified XOR decomposition).
__global__ __launch_bounds__(512, 4) void triplet_main(
        const unsigned short* __restrict__ Xb,
        const int* __restrict__ lbl,
        const float* __restrict__ sq,
        unsigned* __restrict__ ap2,
        unsigned* __restrict__ an2) {
    __shared__ unsigned short Bs[4][64 * D];   // 64 KB; Bs[0..1] stage A first

    const int bi = blockIdx.x >> 3;            // /CPS
    const int c  = blockIdx.x & 7;
    const int jt0 = c * TPC;
    const int i0 = bi * 128;

    const int tid = threadIdx.x;
    const int w = tid >> 6;        // wave 0..7
    const int lane = tid & 63;
    const int wr = w >> 1;         // 0..3 : 32-row group
    const int wc = w & 1;          // 0..1 : 32-col group
    const int quad = lane >> 4;
    const int lx = lane & 15;

    // per-lane j-column offsets and swizzled LDS byte base for B reads
    int cb[2];
    unsigned vb[2];
    #pragma unroll
    for (int tc = 0; tc < 2; ++tc) {
        int rB = wc * 32 + tc * 16 + lx;
        cb[tc] = rB;
        vb[tc] = (unsigned)(rB * 256 + ((lx & 4) << 4) + ((quad ^ (lx & 3)) << 4));
    }

    // ---- meta for pair 0 (slot 0) issued first: deep in queue, done early ----
    float sqj[2][2][2];   // [slot][tileInPair][tc]
    int   lblj[2][2][2];
    #pragma unroll
    for (int t = 0; t < 2; ++t)
        #pragma unroll
        for (int tc = 0; tc < 2; ++tc) {
            int jc = (jt0 + t) * 64 + cb[tc];
            sqj[0][t][tc] = sq[jc];
            lblj[0][t][tc] = lbl[jc];
        }

    // ---- stage A strip (128 rows) into Bs[0..1] (contiguous 32 KB) ----
    unsigned short* Abase = &Bs[0][0];
    #pragma unroll
    for (int t = 0; t < 4; ++t) {
        int rbase = w * 16 + t * 4;
        int r = rbase + quad;
        int gc = lx ^ (r & 7);
        gload_lds16(Xb + (size_t)(i0 + r) * D + gc * 8, Abase + rbase * D);
    }

    // row labels for this wave's 8 accumulator rows
    int lbl_i[8];
    #pragma unroll
    for (int tr = 0; tr < 2; ++tr)
        #pragma unroll
        for (int v = 0; v < 4; ++v)
            lbl_i[tr * 4 + v] = lbl[i0 + wr * 32 + tr * 16 + quad * 4 + v];

    __syncthreads();   // A staged (full drain)

    // ---- hoist A fragments to registers: af_r[tr][ks], 32 VGPRs ----
    bf16x8 af_r[2][4];
    #pragma unroll
    for (int tr = 0; tr < 2; ++tr) {
        int rA = wr * 32 + tr * 16 + lx;
        #pragma unroll
        for (int ks = 0; ks < 4; ++ks) {
            int sc = (ks * 4 + quad) ^ (lx & 7);
            af_r[tr][ks] = *reinterpret_cast<const bf16x8*>(&Abase[rA * D + sc * 8]);
        }
    }
    __syncthreads();   // full drain: all waves' af_r reads done -> Bs reusable

    // ---- stage pair 0 into Bs[0..1] ----
    #pragma unroll
    for (int t = 0; t < 2; ++t) {
        #pragma unroll
        for (int tt = 0; tt < 2; ++tt) {
            int rbase = w * 8 + tt * 4;
            int r = rbase + quad;
            int gc = lx ^ (r & 7);
            gload_lds16(Xb + (size_t)((jt0 + t) * 64 + r) * D + gc * 8,
                        &Bs[t][0] + rbase * D);
        }
    }

    float m_ap[8], m_an[8];
    #pragma unroll
    for (int q = 0; q < 8; ++q) { m_ap[q] = -INFINITY; m_an[q] = INFINITY; }
    const f32x4 z4 = {0.f, 0.f, 0.f, 0.f};

    __syncthreads();   // pair 0 staged

    #pragma unroll 2
    for (int ep = 0; ep < NEP; ++ep) {
        const int p = ep & 1, pn = p ^ 1;
        const int j0 = jt0 + 2 * ep;

        // ---- prefetch next pair (tiles + meta); drained by end-of-epoch sync ----
        if (ep + 1 < NEP) {
            const int jn = j0 + 2;
            #pragma unroll
            for (int t = 0; t < 2; ++t) {
                #pragma unroll
                for (int tt = 0; tt < 2; ++tt) {
                    int rbase = w * 8 + tt * 4;
                    int r = rbase + quad;
                    int gc = lx ^ (r & 7);
                    gload_lds16(Xb + (size_t)((jn + t) * 64 + r) * D + gc * 8,
                                &Bs[2 * pn + t][0] + rbase * D);
                }
            }
            #pragma unroll
            for (int t = 0; t < 2; ++t)
                #pragma unroll
                for (int tc = 0; tc < 2; ++tc) {
                    int jc = (jn + t) * 64 + cb[tc];
                    sqj[pn][t][tc] = sq[jc];
                    lblj[pn][t][tc] = lbl[jc];
                }
        }

        // ---- compute both tiles of the current pair ----
        #pragma unroll
        for (int t = 0; t < 2; ++t) {
            const char* bsb = (const char*)&Bs[2 * p + t][0];

            f32x4 acc[2][2];
            {
                bf16x8 bf0[2];
                #pragma unroll
                for (int tc = 0; tc < 2; ++tc)
                    bf0[tc] = *reinterpret_cast<const bf16x8*>(bsb + vb[tc]);
                #pragma unroll
                for (int tr = 0; tr < 2; ++tr)
                    #pragma unroll
                    for (int tc = 0; tc < 2; ++tc)
                        acc[tr][tc] = __builtin_amdgcn_mfma_f32_16x16x32_bf16(
                            af_r[tr][0], bf0[tc], z4, 0, 0, 0);
            }
            #pragma unroll
            for (int ks = 1; ks < 4; ++ks) {
                bf16x8 bf[2];
                #pragma unroll
                for (int tc = 0; tc < 2; ++tc)
                    bf[tc] = *reinterpret_cast<const bf16x8*>(
                        bsb + (vb[tc] ^ (unsigned)(ks << 6)));
                #pragma unroll
                for (int tr = 0; tr < 2; ++tr)
                    #pragma unroll
                    for (int tc = 0; tc < 2; ++tc)
                        acc[tr][tc] = __builtin_amdgcn_mfma_f32_16x16x32_bf16(
                            af_r[tr][ks], bf[tc], acc[tr][tc], 0, 0, 0);
            }

            // ---- mining epilogue (hides the pair prefetch flight) ----
            #pragma unroll
            for (int tc = 0; tc < 2; ++tc) {
                #pragma unroll
                for (int tr = 0; tr < 2; ++tr) {
                    #pragma unroll
                    for (int v = 0; v < 4; ++v) {
                        int q = tr * 4 + v;
                        float vi = fmaf(-2.f, acc[tr][tc][v], sqj[p][t][tc]);
                        bool same = (lblj[p][t][tc] == lbl_i[q]);
                        m_ap[q] = same ? fmaxf(m_ap[q], vi) : m_ap[q];
                        m_an[q] = same ? m_an[q] : fminf(m_an[q], vi);
                    }
                }
            }
        }

        __syncthreads();   // publishes next pair; drains its (old) prefetch
    }

    // reduce over the 16 j-lanes, then one atomic pair per row (lx==0 lanes)
    #pragma unroll
    for (int off = 8; off >= 1; off >>= 1) {
        #pragma unroll
        for (int q = 0; q < 8; ++q) {
            m_ap[q] = fmaxf(m_ap[q], __shfl_xor(m_ap[q], off));
            m_an[q] = fminf(m_an[q], __shfl_xor(m_an[q], off));
        }
    }
    if (lx == 0) {
        #pragma unroll
        for (int tr = 0; tr < 2; ++tr) {
            #pragma unroll
            for (int v = 0; v < 4; ++v) {
                int q = tr * 4 + v;
                int row = i0 + wr * 32 + tr * 16 + quad * 4 + v;
                float sqi = sq[row];
                float vap = fmaxf(sqi + m_ap[q], 1e-12f);
                float van = fmaxf(sqi + m_an[q], 1e-12f);
                atomicMax(&ap2[row], __float_as_uint(vap));
                atomicMin(&an2[row], __float_as_uint(van));
            }
        }
    }
}

// ---------- finalize: sqrt + hinge + mean ----------
__global__ __launch_bounds__(1024) void finalize_kernel(const unsigned* __restrict__ ap2,
                                                        const unsigned* __restrict__ an2,
                                                        float* __restrict__ out) {
    int tid = threadIdx.x;
    float ls = 0.f, ps = 0.f;
    for (int row = tid; row < N; row += 1024) {
        float ap = sqrtf(__uint_as_float(ap2[row]));
        float an = sqrtf(__uint_as_float(an2[row]));
        ls += fmaxf(0.f, MARGIN - (an - ap));
        ps += (an > ap) ? 1.f : 0.f;
    }
    #pragma unroll
    for (int off = 32; off >= 1; off >>= 1) {
        ls += __shfl_xor(ls, off);
        ps += __shfl_xor(ps, off);
    }
    __shared__ float red[2][16];
    int w = tid >> 6;
    if ((tid & 63) == 0) { red[0][w] = ls; red[1][w] = ps; }
    __syncthreads();
    if (tid == 0) {
        float L = 0.f, P = 0.f;
        #pragma unroll
        for (int i = 0; i < 16; ++i) { L += red[0][i]; P += red[1][i]; }
        out[0] = L / (float)N;
        out[1] = P / (float)N;
    }
}

extern "C" void kernel_launch(void* const* d_in, const int* in_sizes, int n_in,
                              void* d_out, int out_size, void* d_ws, size_t ws_size,
                              hipStream_t stream) {
    const float* X = (const float*)d_in[0];
    const int* lbl = (const int*)d_in[1];
    float* out = (float*)d_out;

    float* sq = (float*)d_ws;                               // N floats
    unsigned* ap2 = (unsigned*)d_ws + N;                    // N uints
    unsigned* an2 = (unsigned*)d_ws + 2 * N;                // N uints
    unsigned short* Xb = (unsigned short*)((char*)d_ws + 3 * N * sizeof(unsigned)); // N*D bf16

    convert_kernel<<<N / 16, 256, 0, stream>>>(X, Xb, sq, ap2, an2);
    triplet_main<<<GRID_MAIN, 512, 0, stream>>>(Xb, lbl, sq, ap2, an2);
    finalize_kernel<<<1, 1024, 0, stream>>>(ap2, an2, out);
}

// Round 8
// 102.272 us; speedup vs baseline: 1.2762x; 1.1052x over previous
//
#include <hip/hip_runtime.h>
#include <hip/hip_bf16.h>
#include <math.h>

#define N 8192
#define D 128
#define MARGIN 0.3f

#define NSTRIP 64            // 128-row strips
#define CPS 8                // j-chunks per strip
#define TPC 16               // 64-col j-tiles per chunk (8*16 = 128, uniform)
#define GRID_MAIN (NSTRIP * CPS)   // 512 = exactly 2 blocks/CU

typedef float f32x4 __attribute__((ext_vector_type(4)));
typedef short bf16x8 __attribute__((ext_vector_type(8)));
typedef unsigned short u16x8 __attribute__((ext_vector_type(8)));

#define AS1 __attribute__((address_space(1)))
#define AS3 __attribute__((address_space(3)))

__device__ inline void gload_lds16(const void* g, void* l) {
    __builtin_amdgcn_global_load_lds((AS1 void*)(void*)(g), (AS3 void*)(l), 16, 0, 0);
}

__device__ inline unsigned short f2bf(float f) {
    unsigned u = __float_as_uint(f);
    unsigned r = (u + 0x7FFFu + ((u >> 16) & 1u)) >> 16;
    return (unsigned short)r;
}

// ---------- convert fp32 -> bf16 + row norms + init mining arrays ----------
__global__ __launch_bounds__(256) void convert_kernel(const float* __restrict__ X,
                                                      unsigned short* __restrict__ Xb,
                                                      float* __restrict__ sq,
                                                      unsigned* __restrict__ ap2,
                                                      unsigned* __restrict__ an2) {
    int tid = threadIdx.x;
    int row = blockIdx.x * 16 + (tid >> 4);
    int l = tid & 15;
    const float4* p = reinterpret_cast<const float4*>(X + (size_t)row * D + l * 8);
    float4 u = p[0];
    float4 v = p[1];
    float s = u.x*u.x + u.y*u.y + u.z*u.z + u.w*u.w
            + v.x*v.x + v.y*v.y + v.z*v.z + v.w*v.w;
    u16x8 o;
    o[0] = f2bf(u.x); o[1] = f2bf(u.y); o[2] = f2bf(u.z); o[3] = f2bf(u.w);
    o[4] = f2bf(v.x); o[5] = f2bf(v.y); o[6] = f2bf(v.z); o[7] = f2bf(v.w);
    *reinterpret_cast<u16x8*>(Xb + (size_t)row * D + l * 8) = o;
    #pragma unroll
    for (int off = 8; off >= 1; off >>= 1) s += __shfl_xor(s, off);
    if (l == 0) {
        sq[row] = s;
        ap2[row] = 0u;            // 0.0f  (< any clipped d2)
        an2[row] = 0x7F7F7F7Fu;   // huge  (> any d2)
    }
}

// ---------- main: full-Gram, i-mining only, paired-epoch LDS prefetch ----------
// r6 lesson (rule #20): runtime-indexed metadata register arrays spilled to
// scratch (+40 MB FETCH/WRITE). r7 lesson: loop-carried runtime LDS pointer
// ping-pong aborted on device. This version: the 2-epoch ping-pong is
// MANUALLY UNROLLED into two phases with COMPILE-TIME buffer indices
// (Bs[0..1] <-> Bs[2..3]); per-tile metadata in named scalars. Each phase
// stages the other pair (2 tiles) then computes its own pair (~2x400 cy of
// ds_read+MFMA+mining) before the barrier drains the staging flight ->
// latency hidden, one barrier per 2 tiles (8 total vs r3's 16).
// A-strip staged through Bs[0..1] once, held in regs (af_r).
// 64 KB LDS -> 2 blocks/CU, 16 waves/CU.
// LDS layout per 64-row buffer: chunk slot s of row r holds global chunk
// s^(r&7); read addr = vb ^ (ks<<6) (verified XOR decomposition).
__global__ __launch_bounds__(512, 4) void triplet_main(
        const unsigned short* __restrict__ Xb,
        const int* __restrict__ lbl,
        const float* __restrict__ sq,
        unsigned* __restrict__ ap2,
        unsigned* __restrict__ an2) {
    __shared__ unsigned short Bs[4][64 * D];   // 64 KB; Bs[0..1] stage A first

    const int bi = blockIdx.x >> 3;            // /CPS
    const int c  = blockIdx.x & 7;
    const int jt0 = c * TPC;
    const int i0 = bi * 128;

    const int tid = threadIdx.x;
    const int w = tid >> 6;        // wave 0..7
    const int lane = tid & 63;
    const int wr = w >> 1;         // 0..3 : 32-row group
    const int wc = w & 1;          // 0..1 : 32-col group
    const int quad = lane >> 4;
    const int lx = lane & 15;

    // per-lane j-column offsets and swizzled LDS byte base for B reads
    int cb[2];
    unsigned vb[2];
    #pragma unroll
    for (int tc = 0; tc < 2; ++tc) {
        int rB = wc * 32 + tc * 16 + lx;
        cb[tc] = rB;
        vb[tc] = (unsigned)(rB * 256 + ((lx & 4) << 4) + ((quad ^ (lx & 3)) << 4));
    }

    // ---- stage A strip (128 rows) into Bs[0..1] (contiguous 32 KB) ----
    unsigned short* Abase = &Bs[0][0];
    #pragma unroll
    for (int t = 0; t < 4; ++t) {
        int rbase = w * 16 + t * 4;
        int r = rbase + quad;
        int gc = lx ^ (r & 7);
        gload_lds16(Xb + (size_t)(i0 + r) * D + gc * 8, Abase + rbase * D);
    }

    // row labels for this wave's 8 accumulator rows (hidden under A staging)
    int lbl_i[8];
    #pragma unroll
    for (int tr = 0; tr < 2; ++tr)
        #pragma unroll
        for (int v = 0; v < 4; ++v)
            lbl_i[tr * 4 + v] = lbl[i0 + wr * 32 + tr * 16 + quad * 4 + v];

    __syncthreads();   // A staged (full drain)

    // ---- hoist A fragments to registers: af_r[tr][ks], 32 VGPRs ----
    bf16x8 af_r[2][4];
    #pragma unroll
    for (int tr = 0; tr < 2; ++tr) {
        int rA = wr * 32 + tr * 16 + lx;
        #pragma unroll
        for (int ks = 0; ks < 4; ++ks) {
            int sc = (ks * 4 + quad) ^ (lx & 7);
            af_r[tr][ks] = *reinterpret_cast<const bf16x8*>(&Abase[rA * D + sc * 8]);
        }
    }
    __syncthreads();   // full drain: all waves' af_r reads done -> Bs reusable

    float m_ap[8], m_an[8];
    #pragma unroll
    for (int q = 0; q < 8; ++q) { m_ap[q] = -INFINITY; m_an[q] = INFINITY; }
    const f32x4 z4 = {0.f, 0.f, 0.f, 0.f};

    // stage one 64-row j-tile into buf (wave-cooperative, 2 gload per wave)
    auto stage_tile = [&](unsigned short* buf, int jj) {
        #pragma unroll
        for (int tt = 0; tt < 2; ++tt) {
            int rbase = w * 8 + tt * 4;
            int r = rbase + quad;
            int gc = lx ^ (r & 7);
            gload_lds16(Xb + (size_t)(jj * 64 + r) * D + gc * 8, buf + rbase * D);
        }
    };

    // compute one tile from buf: MFMA + i-direction mining
    auto compute_tile = [&](const unsigned short* buf, int jj) {
        const char* bsb = (const char*)buf;
        // per-tile metadata: named scalars, static indexing (no spill)
        int jc0 = jj * 64 + cb[0];
        int jc1 = jj * 64 + cb[1];
        float sqj0 = sq[jc0]; int lbj0 = lbl[jc0];
        float sqj1 = sq[jc1]; int lbj1 = lbl[jc1];

        f32x4 acc[2][2];
        {
            bf16x8 bf0[2];
            #pragma unroll
            for (int tc = 0; tc < 2; ++tc)
                bf0[tc] = *reinterpret_cast<const bf16x8*>(bsb + vb[tc]);
            #pragma unroll
            for (int tr = 0; tr < 2; ++tr)
                #pragma unroll
                for (int tc = 0; tc < 2; ++tc)
                    acc[tr][tc] = __builtin_amdgcn_mfma_f32_16x16x32_bf16(
                        af_r[tr][0], bf0[tc], z4, 0, 0, 0);
        }
        #pragma unroll
        for (int ks = 1; ks < 4; ++ks) {
            bf16x8 bf[2];
            #pragma unroll
            for (int tc = 0; tc < 2; ++tc)
                bf[tc] = *reinterpret_cast<const bf16x8*>(
                    bsb + (vb[tc] ^ (unsigned)(ks << 6)));
            #pragma unroll
            for (int tr = 0; tr < 2; ++tr)
                #pragma unroll
                for (int tc = 0; tc < 2; ++tc)
                    acc[tr][tc] = __builtin_amdgcn_mfma_f32_16x16x32_bf16(
                        af_r[tr][ks], bf[tc], acc[tr][tc], 0, 0, 0);
        }

        #pragma unroll
        for (int tc = 0; tc < 2; ++tc) {
            float sqjv = tc ? sqj1 : sqj0;
            int lbjv = tc ? lbj1 : lbj0;
            #pragma unroll
            for (int tr = 0; tr < 2; ++tr) {
                #pragma unroll
                for (int v = 0; v < 4; ++v) {
                    int q = tr * 4 + v;
                    float vi = fmaf(-2.f, acc[tr][tc][v], sqjv);
                    bool same = (lbjv == lbl_i[q]);
                    m_ap[q] = same ? fmaxf(m_ap[q], vi) : m_ap[q];
                    m_an[q] = same ? m_an[q] : fminf(m_an[q], vi);
                }
            }
        }
    };

    // ---- stage pair 0 (tiles jt0, jt0+1) into Bs[0..1] ----
    stage_tile(&Bs[0][0], jt0);
    stage_tile(&Bs[1][0], jt0 + 1);
    __syncthreads();   // pair 0 staged

    // ---- main loop: 4 macro-iterations x 2 statically-indexed phases ----
    #pragma unroll 1
    for (int e = 0; e < 4; ++e) {
        const int jb = jt0 + 4 * e;

        // phase A: prefetch pair (jb+2, jb+3) -> Bs[2..3]; compute Bs[0..1]
        stage_tile(&Bs[2][0], jb + 2);
        stage_tile(&Bs[3][0], jb + 3);
        compute_tile(&Bs[0][0], jb);
        compute_tile(&Bs[1][0], jb + 1);
        __syncthreads();   // drains phase-A prefetch (issued ~2 tiles ago)

        // phase B: prefetch pair (jb+4, jb+5) -> Bs[0..1]; compute Bs[2..3]
        if (e < 3) {
            stage_tile(&Bs[0][0], jb + 4);
            stage_tile(&Bs[1][0], jb + 5);
        }
        compute_tile(&Bs[2][0], jb + 2);
        compute_tile(&Bs[3][0], jb + 3);
        __syncthreads();   // drains phase-B prefetch
    }

    // reduce over the 16 j-lanes, then one atomic pair per row (lx==0 lanes)
    #pragma unroll
    for (int off = 8; off >= 1; off >>= 1) {
        #pragma unroll
        for (int q = 0; q < 8; ++q) {
            m_ap[q] = fmaxf(m_ap[q], __shfl_xor(m_ap[q], off));
            m_an[q] = fminf(m_an[q], __shfl_xor(m_an[q], off));
        }
    }
    if (lx == 0) {
        #pragma unroll
        for (int tr = 0; tr < 2; ++tr) {
            #pragma unroll
            for (int v = 0; v < 4; ++v) {
                int q = tr * 4 + v;
                int row = i0 + wr * 32 + tr * 16 + quad * 4 + v;
                float sqi = sq[row];
                float vap = fmaxf(sqi + m_ap[q], 1e-12f);
                float van = fmaxf(sqi + m_an[q], 1e-12f);
                atomicMax(&ap2[row], __float_as_uint(vap));
                atomicMin(&an2[row], __float_as_uint(van));
            }
        }
    }
}

// ---------- finalize: sqrt + hinge + mean ----------
__global__ __launch_bounds__(1024) void finalize_kernel(const unsigned* __restrict__ ap2,
                                                        const unsigned* __restrict__ an2,
                                                        float* __restrict__ out) {
    int tid = threadIdx.x;
    float ls = 0.f, ps = 0.f;
    for (int row = tid; row < N; row += 1024) {
        float ap = sqrtf(__uint_as_float(ap2[row]));
        float an = sqrtf(__uint_as_float(an2[row]));
        ls += fmaxf(0.f, MARGIN - (an - ap));
        ps += (an > ap) ? 1.f : 0.f;
    }
    #pragma unroll
    for (int off = 32; off >= 1; off >>= 1) {
        ls += __shfl_xor(ls, off);
        ps += __shfl_xor(ps, off);
    }
    __shared__ float red[2][16];
    int w = tid >> 6;
    if ((tid & 63) == 0) { red[0][w] = ls; red[1][w] = ps; }
    __syncthreads();
    if (tid == 0) {
        float L = 0.f, P = 0.f;
        #pragma unroll
        for (int i = 0; i < 16; ++i) { L += red[0][i]; P += red[1][i]; }
        out[0] = L / (float)N;
        out[1] = P / (float)N;
    }
}

extern "C" void kernel_launch(void* const* d_in, const int* in_sizes, int n_in,
                              void* d_out, int out_size, void* d_ws, size_t ws_size,
                              hipStream_t stream) {
    const float* X = (const float*)d_in[0];
    const int* lbl = (const int*)d_in[1];
    float* out = (float*)d_out;

    float* sq = (float*)d_ws;                               // N floats
    unsigned* ap2 = (unsigned*)d_ws + N;                    // N uints
    unsigned* an2 = (unsigned*)d_ws + 2 * N;                // N uints
    unsigned short* Xb = (unsigned short*)((char*)d_ws + 3 * N * sizeof(unsigned)); // N*D bf16

    convert_kernel<<<N / 16, 256, 0, stream>>>(X, Xb, sq, ap2, an2);
    triplet_main<<<GRID_MAIN, 512, 0, stream>>>(Xb, lbl, sq, ap2, an2);
    finalize_kernel<<<1, 1024, 0, stream>>>(ap2, an2, out);
}

// Round 9
// 101.364 us; speedup vs baseline: 1.2876x; 1.0090x over previous
//
#include <hip/hip_runtime.h>
#include <hip/hip_bf16.h>
#include <math.h>

#define N 8192
#define D 128
#define MARGIN 0.3f

#define NSTRIP 64            // 128-row strips
#define CPS 8                // j-chunks per strip
#define TPC 16               // 64-col j-tiles per chunk (8*16 = 128, uniform)
#define GRID_MAIN (NSTRIP * CPS)   // 512 = exactly 2 blocks/CU

typedef float f32x4 __attribute__((ext_vector_type(4)));
typedef short bf16x8 __attribute__((ext_vector_type(8)));
typedef unsigned short u16x8 __attribute__((ext_vector_type(8)));

#define AS1 __attribute__((address_space(1)))
#define AS3 __attribute__((address_space(3)))

__device__ inline void gload_lds16(const void* g, void* l) {
    __builtin_amdgcn_global_load_lds((AS1 void*)(void*)(g), (AS3 void*)(l), 16, 0, 0);
}

__device__ inline unsigned short f2bf(float f) {
    unsigned u = __float_as_uint(f);
    unsigned r = (u + 0x7FFFu + ((u >> 16) & 1u)) >> 16;
    return (unsigned short)r;
}

// ---------- convert fp32 -> bf16 + row norms + init mining arrays ----------
__global__ __launch_bounds__(256) void convert_kernel(const float* __restrict__ X,
                                                      unsigned short* __restrict__ Xb,
                                                      float* __restrict__ sq,
                                                      unsigned* __restrict__ ap2,
                                                      unsigned* __restrict__ an2) {
    int tid = threadIdx.x;
    int row = blockIdx.x * 16 + (tid >> 4);
    int l = tid & 15;
    const float4* p = reinterpret_cast<const float4*>(X + (size_t)row * D + l * 8);
    float4 u = p[0];
    float4 v = p[1];
    float s = u.x*u.x + u.y*u.y + u.z*u.z + u.w*u.w
            + v.x*v.x + v.y*v.y + v.z*v.z + v.w*v.w;
    u16x8 o;
    o[0] = f2bf(u.x); o[1] = f2bf(u.y); o[2] = f2bf(u.z); o[3] = f2bf(u.w);
    o[4] = f2bf(v.x); o[5] = f2bf(v.y); o[6] = f2bf(v.z); o[7] = f2bf(v.w);
    *reinterpret_cast<u16x8*>(Xb + (size_t)row * D + l * 8) = o;
    #pragma unroll
    for (int off = 8; off >= 1; off >>= 1) s += __shfl_xor(s, off);
    if (l == 0) {
        sq[row] = s;
        ap2[row] = 0u;            // 0.0f  (< any clipped d2)
        an2[row] = 0x7F7F7F7Fu;   // huge  (> any d2)
    }
}

// ---------- main: full-Gram, i-mining only, paired-epoch LDS prefetch ----------
// r8 lesson (vmcnt semantics): metadata (sq/lbl) loaded AFTER the phase's
// prefetch issue forces an in-order vmcnt drain of the prefetch mid-phase --
// the exact serialization pairing was meant to remove (46 us vs r3's 39).
// Fix: ALL 8 metadata scalars for the current pair load at PHASE TOP, before
// the stage issue -> compiler emits a counted vmcnt(4); prefetch stays in
// flight across both tiles' MFMA+mining and is drained by the end-of-phase
// barrier (~600 cy later). Static 2-phase ping-pong (Bs[0..1] <-> Bs[2..3],
// compile-time indices; r7's runtime LDS pointer carry aborted). Metadata in
// named scalars (r6 rule-#20 spill). A-strip staged through Bs[0..1] once,
// held in regs (af_r). 64 KB LDS -> 2 blocks/CU, 16 waves/CU.
// LDS layout per 64-row buffer: chunk slot s of row r holds global chunk
// s^(r&7); read addr = vb ^ (ks<<6) (verified XOR decomposition).
__global__ __launch_bounds__(512, 4) void triplet_main(
        const unsigned short* __restrict__ Xb,
        const int* __restrict__ lbl,
        const float* __restrict__ sq,
        unsigned* __restrict__ ap2,
        unsigned* __restrict__ an2) {
    __shared__ unsigned short Bs[4][64 * D];   // 64 KB; Bs[0..1] stage A first

    const int bi = blockIdx.x >> 3;            // /CPS
    const int c  = blockIdx.x & 7;
    const int jt0 = c * TPC;
    const int i0 = bi * 128;

    const int tid = threadIdx.x;
    const int w = tid >> 6;        // wave 0..7
    const int lane = tid & 63;
    const int wr = w >> 1;         // 0..3 : 32-row group
    const int wc = w & 1;          // 0..1 : 32-col group
    const int quad = lane >> 4;
    const int lx = lane & 15;

    // per-lane j-column offsets and swizzled LDS byte base for B reads
    int cb[2];
    unsigned vb[2];
    #pragma unroll
    for (int tc = 0; tc < 2; ++tc) {
        int rB = wc * 32 + tc * 16 + lx;
        cb[tc] = rB;
        vb[tc] = (unsigned)(rB * 256 + ((lx & 4) << 4) + ((quad ^ (lx & 3)) << 4));
    }

    // ---- stage A strip (128 rows) into Bs[0..1] (contiguous 32 KB) ----
    unsigned short* Abase = &Bs[0][0];
    #pragma unroll
    for (int t = 0; t < 4; ++t) {
        int rbase = w * 16 + t * 4;
        int r = rbase + quad;
        int gc = lx ^ (r & 7);
        gload_lds16(Xb + (size_t)(i0 + r) * D + gc * 8, Abase + rbase * D);
    }

    // row labels for this wave's 8 accumulator rows (hidden under A staging)
    int lbl_i[8];
    #pragma unroll
    for (int tr = 0; tr < 2; ++tr)
        #pragma unroll
        for (int v = 0; v < 4; ++v)
            lbl_i[tr * 4 + v] = lbl[i0 + wr * 32 + tr * 16 + quad * 4 + v];

    __syncthreads();   // A staged (full drain)

    // ---- hoist A fragments to registers: af_r[tr][ks], 32 VGPRs ----
    bf16x8 af_r[2][4];
    #pragma unroll
    for (int tr = 0; tr < 2; ++tr) {
        int rA = wr * 32 + tr * 16 + lx;
        #pragma unroll
        for (int ks = 0; ks < 4; ++ks) {
            int sc = (ks * 4 + quad) ^ (lx & 7);
            af_r[tr][ks] = *reinterpret_cast<const bf16x8*>(&Abase[rA * D + sc * 8]);
        }
    }
    __syncthreads();   // full drain: all waves' af_r reads done -> Bs reusable

    float m_ap[8], m_an[8];
    #pragma unroll
    for (int q = 0; q < 8; ++q) { m_ap[q] = -INFINITY; m_an[q] = INFINITY; }
    const f32x4 z4 = {0.f, 0.f, 0.f, 0.f};

    // stage one 64-row j-tile into buf (wave-cooperative, 2 gload per wave)
    auto stage_tile = [&](unsigned short* buf, int jj) {
        #pragma unroll
        for (int tt = 0; tt < 2; ++tt) {
            int rbase = w * 8 + tt * 4;
            int r = rbase + quad;
            int gc = lx ^ (r & 7);
            gload_lds16(Xb + (size_t)(jj * 64 + r) * D + gc * 8, buf + rbase * D);
        }
    };

    // compute one tile from buf: MFMA + i-direction mining (meta passed in,
    // loaded at phase top BEFORE the prefetch issue -> counted vmcnt)
    auto do_tile = [&](const unsigned short* buf,
                       float sqj0, float sqj1, int lbj0, int lbj1) {
        const char* bsb = (const char*)buf;
        f32x4 acc[2][2];
        {
            bf16x8 bf0[2];
            #pragma unroll
            for (int tc = 0; tc < 2; ++tc)
                bf0[tc] = *reinterpret_cast<const bf16x8*>(bsb + vb[tc]);
            #pragma unroll
            for (int tr = 0; tr < 2; ++tr)
                #pragma unroll
                for (int tc = 0; tc < 2; ++tc)
                    acc[tr][tc] = __builtin_amdgcn_mfma_f32_16x16x32_bf16(
                        af_r[tr][0], bf0[tc], z4, 0, 0, 0);
        }
        #pragma unroll
        for (int ks = 1; ks < 4; ++ks) {
            bf16x8 bf[2];
            #pragma unroll
            for (int tc = 0; tc < 2; ++tc)
                bf[tc] = *reinterpret_cast<const bf16x8*>(
                    bsb + (vb[tc] ^ (unsigned)(ks << 6)));
            #pragma unroll
            for (int tr = 0; tr < 2; ++tr)
                #pragma unroll
                for (int tc = 0; tc < 2; ++tc)
                    acc[tr][tc] = __builtin_amdgcn_mfma_f32_16x16x32_bf16(
                        af_r[tr][ks], bf[tc], acc[tr][tc], 0, 0, 0);
        }

        #pragma unroll
        for (int tc = 0; tc < 2; ++tc) {
            float sqjv = tc ? sqj1 : sqj0;
            int lbjv = tc ? lbj1 : lbj0;
            #pragma unroll
            for (int tr = 0; tr < 2; ++tr) {
                #pragma unroll
                for (int v = 0; v < 4; ++v) {
                    int q = tr * 4 + v;
                    float vi = fmaf(-2.f, acc[tr][tc][v], sqjv);
                    bool same = (lbjv == lbl_i[q]);
                    m_ap[q] = same ? fmaxf(m_ap[q], vi) : m_ap[q];
                    m_an[q] = same ? m_an[q] : fminf(m_an[q], vi);
                }
            }
        }
    };

    // ---- stage pair 0 (tiles jt0, jt0+1) into Bs[0..1] ----
    stage_tile(&Bs[0][0], jt0);
    stage_tile(&Bs[1][0], jt0 + 1);
    __syncthreads();   // pair 0 staged

    // ---- main loop: 4 macro-iterations x 2 statically-indexed phases ----
    #pragma unroll 1
    for (int e = 0; e < 4; ++e) {
        const int jb = jt0 + 4 * e;

        // ===== phase A: meta first -> prefetch (jb+2,jb+3) -> compute Bs[0..1]
        {
            int jcA0 = jb * 64 + cb[0],      jcA1 = jb * 64 + cb[1];
            int jcB0 = (jb + 1) * 64 + cb[0], jcB1 = (jb + 1) * 64 + cb[1];
            float sA0 = sq[jcA0], sA1 = sq[jcA1], sB0 = sq[jcB0], sB1 = sq[jcB1];
            int   lA0 = lbl[jcA0], lA1 = lbl[jcA1], lB0 = lbl[jcB0], lB1 = lbl[jcB1];

            stage_tile(&Bs[2][0], jb + 2);
            stage_tile(&Bs[3][0], jb + 3);

            do_tile(&Bs[0][0], sA0, sA1, lA0, lA1);
            do_tile(&Bs[1][0], sB0, sB1, lB0, lB1);
        }
        __syncthreads();   // drains phase-A prefetch (issued ~2 tiles ago)

        // ===== phase B: meta first -> prefetch (jb+4,jb+5) -> compute Bs[2..3]
        {
            int jcA0 = (jb + 2) * 64 + cb[0], jcA1 = (jb + 2) * 64 + cb[1];
            int jcB0 = (jb + 3) * 64 + cb[0], jcB1 = (jb + 3) * 64 + cb[1];
            float sA0 = sq[jcA0], sA1 = sq[jcA1], sB0 = sq[jcB0], sB1 = sq[jcB1];
            int   lA0 = lbl[jcA0], lA1 = lbl[jcA1], lB0 = lbl[jcB0], lB1 = lbl[jcB1];

            if (e < 3) {
                stage_tile(&Bs[0][0], jb + 4);
                stage_tile(&Bs[1][0], jb + 5);
            }

            do_tile(&Bs[2][0], sA0, sA1, lA0, lA1);
            do_tile(&Bs[3][0], sB0, sB1, lB0, lB1);
        }
        __syncthreads();   // drains phase-B prefetch
    }

    // reduce over the 16 j-lanes, then one atomic pair per row (lx==0 lanes)
    #pragma unroll
    for (int off = 8; off >= 1; off >>= 1) {
        #pragma unroll
        for (int q = 0; q < 8; ++q) {
            m_ap[q] = fmaxf(m_ap[q], __shfl_xor(m_ap[q], off));
            m_an[q] = fminf(m_an[q], __shfl_xor(m_an[q], off));
        }
    }
    if (lx == 0) {
        #pragma unroll
        for (int tr = 0; tr < 2; ++tr) {
            #pragma unroll
            for (int v = 0; v < 4; ++v) {
                int q = tr * 4 + v;
                int row = i0 + wr * 32 + tr * 16 + quad * 4 + v;
                float sqi = sq[row];
                float vap = fmaxf(sqi + m_ap[q], 1e-12f);
                float van = fmaxf(sqi + m_an[q], 1e-12f);
                atomicMax(&ap2[row], __float_as_uint(vap));
                atomicMin(&an2[row], __float_as_uint(van));
            }
        }
    }
}

// ---------- finalize: sqrt + hinge + mean ----------
__global__ __launch_bounds__(1024) void finalize_kernel(const unsigned* __restrict__ ap2,
                                                        const unsigned* __restrict__ an2,
                                                        float* __restrict__ out) {
    int tid = threadIdx.x;
    float ls = 0.f, ps = 0.f;
    for (int row = tid; row < N; row += 1024) {
        float ap = sqrtf(__uint_as_float(ap2[row]));
        float an = sqrtf(__uint_as_float(an2[row]));
        ls += fmaxf(0.f, MARGIN - (an - ap));
        ps += (an > ap) ? 1.f : 0.f;
    }
    #pragma unroll
    for (int off = 32; off >= 1; off >>= 1) {
        ls += __shfl_xor(ls, off);
        ps += __shfl_xor(ps, off);
    }
    __shared__ float red[2][16];
    int w = tid >> 6;
    if ((tid & 63) == 0) { red[0][w] = ls; red[1][w] = ps; }
    __syncthreads();
    if (tid == 0) {
        float L = 0.f, P = 0.f;
        #pragma unroll
        for (int i = 0; i < 16; ++i) { L += red[0][i]; P += red[1][i]; }
        out[0] = L / (float)N;
        out[1] = P / (float)N;
    }
}

extern "C" void kernel_launch(void* const* d_in, const int* in_sizes, int n_in,
                              void* d_out, int out_size, void* d_ws, size_t ws_size,
                              hipStream_t stream) {
    const float* X = (const float*)d_in[0];
    const int* lbl = (const int*)d_in[1];
    float* out = (float*)d_out;

    float* sq = (float*)d_ws;                               // N floats
    unsigned* ap2 = (unsigned*)d_ws + N;                    // N uints
    unsigned* an2 = (unsigned*)d_ws + 2 * N;                // N uints
    unsigned short* Xb = (unsigned short*)((char*)d_ws + 3 * N * sizeof(unsigned)); // N*D bf16

    convert_kernel<<<N / 16, 256, 0, stream>>>(X, Xb, sq, ap2, an2);
    triplet_main<<<GRID_MAIN, 512, 0, stream>>>(Xb, lbl, sq, ap2, an2);
    finalize_kernel<<<1, 1024, 0, stream>>>(ap2, an2, out);
}